// Round 8
// baseline (121.216 us; speedup 1.0000x reference)
//
#include <hip/hip_runtime.h>

// Involution: B=4, C=256, H=W=56, K=7, GC=16 -> G=16, Cr=64, K2=49
// conv1 + conv2 both f16 MFMA (16x16x32), apply fp32 with b128 row loads.
// ws: mid f16 [4][3136 p][64 c] @0 | w1fh f16 [64 o][256 c] BN-folded @1605632 |
//     b1f f32[64] @1638400 | cwb f16 [16 g][64 k][64 c] @1638656

#define EPS 1e-5f

typedef __fp16 half2t __attribute__((ext_vector_type(2)));
typedef __fp16 half8t __attribute__((ext_vector_type(8)));
typedef float floatx4 __attribute__((ext_vector_type(4)));

// ---------------- Kernel 0: weight prep ----------------
__global__ __launch_bounds__(256) void k0_setup(
    const float* __restrict__ w1, const float* __restrict__ gamma,
    const float* __restrict__ beta, const float* __restrict__ mean,
    const float* __restrict__ var, const float* __restrict__ cw,
    __fp16* __restrict__ w1fh, float* __restrict__ b1f,
    __fp16* __restrict__ cwb)
{
    const int tid = blockIdx.x * 256 + threadIdx.x;
    const int n   = gridDim.x * 256;
    for (int idx = tid; idx < 16384; idx += n) {        // w1fh[o][c]
        int o = idx >> 8;
        float s = gamma[o] * rsqrtf(var[o] + EPS);
        w1fh[idx] = (__fp16)(w1[idx] * s);
    }
    for (int idx = tid; idx < 64; idx += n) {           // b1f[o]
        float s = gamma[idx] * rsqrtf(var[idx] + EPS);
        b1f[idx] = beta[idx] - mean[idx] * s;
    }
    for (int idx = tid; idx < 65536; idx += n) {        // cwb[g][k][c]
        int g = idx >> 12, k = (idx >> 6) & 63, c = idx & 63;
        cwb[idx] = (__fp16)((k < 49) ? cw[(g * 49 + k) * 64 + c] : 0.f);
    }
}

// ---------------- Kernel 1: conv1 (1x1, 256->64) + BN + ReLU, MFMA ----------
// grid (49,4): block 64o x 64px, K=256 in 4 chunks. A-frags from global (L2).
__global__ __launch_bounds__(256, 2) void k1_conv1(
    const float* __restrict__ x, const __fp16* __restrict__ w1fh,
    const float* __restrict__ b1f, __fp16* __restrict__ mid)
{
    __shared__ __align__(16) __fp16 lxB[64 * 72];    // [px][c-chunk], stride 72
    const int t    = threadIdx.x;
    const int b    = blockIdx.y;
    const int p0   = blockIdx.x * 64;
    const int lane = t & 63, wvid = t >> 6;
    const int mrow = lane & 15, quad = lane >> 4;

    // hoist all A-fragments (o-row of this lane, 4 chunks x 2 k-halves)
    const int orow = wvid * 16 + mrow;
    half8t A[4][2];
#pragma unroll
    for (int ch = 0; ch < 4; ++ch)
#pragma unroll
        for (int h = 0; h < 2; ++h)
            A[ch][h] = *(const half8t*)&w1fh[orow * 256 + ch * 64 + h * 32 + quad * 8];

    floatx4 acc[4] = {};
    const int c2 = t & 31, pxo = t >> 5;             // staging: c-pair, px-octet
    for (int ch = 0; ch < 4; ++ch) {
        // stage B: rows c=2*c2, 2*c2+1 at px pxo*8..+7 -> [px][c] f16
        const float* r0 = &x[(size_t)(b * 256 + ch * 64 + 2 * c2) * 3136 + p0 + pxo * 8];
        const float* r1 = r0 + 3136;
        float4 a0 = *(const float4*)r0, a1 = *(const float4*)(r0 + 4);
        float4 b0 = *(const float4*)r1, b1 = *(const float4*)(r1 + 4);
        const float* f0 = (const float*)&a0;
        const float* f1 = (const float*)&b0;
#pragma unroll
        for (int j = 0; j < 4; ++j) {
            half2t q = __builtin_amdgcn_cvt_pkrtz(f0[j], f1[j]);
            *(half2t*)&lxB[(pxo * 8 + j) * 72 + 2 * c2] = q;
        }
        const float* g0 = (const float*)&a1;
        const float* g1 = (const float*)&b1;
#pragma unroll
        for (int j = 0; j < 4; ++j) {
            half2t q = __builtin_amdgcn_cvt_pkrtz(g0[j], g1[j]);
            *(half2t*)&lxB[(pxo * 8 + 4 + j) * 72 + 2 * c2] = q;
        }
        __syncthreads();
#pragma unroll
        for (int pt = 0; pt < 4; ++pt) {
            half8t bf0 = *(const half8t*)&lxB[(pt * 16 + mrow) * 72 + quad * 8];
            half8t bf1 = *(const half8t*)&lxB[(pt * 16 + mrow) * 72 + quad * 8 + 32];
            acc[pt] = __builtin_amdgcn_mfma_f32_16x16x32_f16(A[ch][0], bf0, acc[pt], 0, 0, 0);
            acc[pt] = __builtin_amdgcn_mfma_f32_16x16x32_f16(A[ch][1], bf1, acc[pt], 0, 0, 0);
        }
        __syncthreads();
    }
    // epilogue: bias + relu -> f16, transpose via lxB, coalesced b128 out
    float bb[4];
#pragma unroll
    for (int i = 0; i < 4; ++i) bb[i] = b1f[wvid * 16 + quad * 4 + i];
#pragma unroll
    for (int pt = 0; pt < 4; ++pt)
#pragma unroll
        for (int i = 0; i < 4; ++i) {
            float v = fmaxf(acc[pt][i] + bb[i], 0.f);
            lxB[(pt * 16 + mrow) * 72 + wvid * 16 + quad * 4 + i] = (__fp16)v;
        }
    __syncthreads();
#pragma unroll
    for (int it = 0; it < 2; ++it) {
        int slot = t + it * 256;                     // 512 slots
        int px = slot >> 3, o8 = slot & 7;
        *(half8t*)&mid[(size_t)(b * 3136 + p0 + px) * 64 + o8 * 8] =
            *(const half8t*)&lxB[px * 72 + o8 * 8];
    }
}

// ---------------- Kernel 2: fused conv2 (f16 MFMA) + unfold/apply (fp32) ----
__global__ __launch_bounds__(256, 5) void k23_fused(
    const float* __restrict__ x, const __fp16* __restrict__ mid,
    const __fp16* __restrict__ cwb, const float* __restrict__ cb,
    float* __restrict__ out)
{
    // lmid[64px][72] f16 (9216 B) overlaid by lx[16ch][228] f32 (14592 B);
    // lw2[49][68] f32 at 14592 (13328 B). total 27920 B.
    __shared__ __align__(16) unsigned char smem[27920];
    __fp16* lmid = (__fp16*)smem;
    float*  lx   = (float*)smem;
    float*  lw2  = (float*)(smem + 14592);

    const int t  = threadIdx.x;
    const int b  = blockIdx.z;
    const int g  = blockIdx.y;
    const int th = blockIdx.x / 7, tw = blockIdx.x % 7;
    const int h0 = th * 8, w0 = tw * 8;
    const int lane = t & 63, wvid = t >> 6;
    const int mrow = lane & 15, quad = lane >> 4;

    // A-fragments straight from global (L2-hot, 8 KB per g)
    half8t a0 = *(const half8t*)&cwb[g * 4096 + (wvid * 16 + mrow) * 64 + quad * 8];
    half8t a1 = *(const half8t*)&cwb[g * 4096 + (wvid * 16 + mrow) * 64 + quad * 8 + 32];

    // stage lmid [px][c] (stride 72): contiguous-slot b128 copies
#pragma unroll
    for (int i = 0; i < 2; ++i) {
        int s  = t + i * 256;                        // 512 slots
        int px = s >> 3, c8 = s & 7;
        int pix = (h0 + (px >> 3)) * 56 + w0 + (px & 7);
        *(half8t*)&lmid[px * 72 + c8 * 8] =
            *(const half8t*)&mid[(size_t)(b * 3136 + pix) * 64 + c8 * 8];
    }
    // prefetch x halo (16ch x 14x14 = 3136) into registers
    float rv[13];
#pragma unroll
    for (int i = 0; i < 13; ++i) {
        int idx = t + i * 256;
        float v = 0.f;
        if (idx < 3136) {
            int ch = idx / 196, r = idx % 196;
            int rr = r / 14, col = r % 14;
            int gh = h0 + rr - 3, gw = w0 + col - 3;
            if (gh >= 0 && gh < 56 && gw >= 0 && gw < 56)
                v = x[(b * 256 + g * 16 + ch) * 3136 + gh * 56 + gw];
        }
        rv[i] = v;
    }
    __syncthreads();

    // MFMA GEMM: D[ko][px] = sum_c W[ko][c] * M[c][px]
    {
        float bias[4];
        int   kor[4];
#pragma unroll
        for (int i = 0; i < 4; ++i) {
            kor[i]  = wvid * 16 + quad * 4 + i;
            bias[i] = (kor[i] < 49) ? cb[g * 49 + kor[i]] : 0.f;
        }
#pragma unroll
        for (int pt = 0; pt < 4; ++pt) {
            half8t b0 = *(const half8t*)&lmid[(pt * 16 + mrow) * 72 + quad * 8];
            half8t b1 = *(const half8t*)&lmid[(pt * 16 + mrow) * 72 + quad * 8 + 32];
            floatx4 acc = {0.f, 0.f, 0.f, 0.f};
            acc = __builtin_amdgcn_mfma_f32_16x16x32_f16(a0, b0, acc, 0, 0, 0);
            acc = __builtin_amdgcn_mfma_f32_16x16x32_f16(a1, b1, acc, 0, 0, 0);
#pragma unroll
            for (int i = 0; i < 4; ++i)
                if (kor[i] < 49)
                    lw2[kor[i] * 68 + pt * 16 + mrow] = acc[i] + bias[i];
        }
    }
    __syncthreads();

    // halo regs -> LDS: ch stride 228 (=4 mod 32), row stride 16 (b128-aligned)
#pragma unroll
    for (int i = 0; i < 13; ++i) {
        int idx = t + i * 256;
        if (idx < 3136) {
            int ch = idx / 196, r = idx % 196;
            lx[ch * 228 + (r / 14) * 16 + (r % 14)] = rv[i];
        }
    }
    __syncthreads();

    // apply: thread = (cc = t>>4, 4 consecutive out px), fp32, b128 row loads
    const int cc = t >> 4, pxt = t & 15;
    const int sh = pxt >> 1, sw4 = (pxt & 1) * 4;
    float a0f = 0.f, a1f = 0.f, a2f = 0.f, a3f = 0.f;
#pragma unroll
    for (int kh = 0; kh < 7; ++kh) {
        const float* row = &lx[cc * 228 + (sh + kh) * 16 + sw4];
        float4 x0 = *(const float4*)row;
        float4 x1 = *(const float4*)(row + 4);
        float4 x2 = *(const float4*)(row + 8);
        float xr[12];
        xr[0] = x0.x; xr[1] = x0.y; xr[2]  = x0.z; xr[3]  = x0.w;
        xr[4] = x1.x; xr[5] = x1.y; xr[6]  = x1.z; xr[7]  = x1.w;
        xr[8] = x2.x; xr[9] = x2.y; xr[10] = x2.z; xr[11] = x2.w;
#pragma unroll
        for (int kw = 0; kw < 7; ++kw) {
            const float4 wv = *(const float4*)&lw2[(kh * 7 + kw) * 68 + pxt * 4];
            a0f = fmaf(wv.x, xr[kw + 0], a0f);
            a1f = fmaf(wv.y, xr[kw + 1], a1f);
            a2f = fmaf(wv.z, xr[kw + 2], a2f);
            a3f = fmaf(wv.w, xr[kw + 3], a3f);
        }
    }
    *(float4*)&out[(b * 256 + g * 16 + cc) * 3136 + (h0 + sh) * 56 + w0 + sw4] =
        make_float4(a0f, a1f, a2f, a3f);
}

extern "C" void kernel_launch(void* const* d_in, const int* in_sizes, int n_in,
                              void* d_out, int out_size, void* d_ws, size_t ws_size,
                              hipStream_t stream) {
    const float* x     = (const float*)d_in[0];
    const float* w1    = (const float*)d_in[1];
    const float* gamma = (const float*)d_in[2];
    const float* beta  = (const float*)d_in[3];
    const float* mean  = (const float*)d_in[4];
    const float* var   = (const float*)d_in[5];
    const float* cw    = (const float*)d_in[6];
    const float* cb    = (const float*)d_in[7];
    float* out = (float*)d_out;

    unsigned char* ws = (unsigned char*)d_ws;
    __fp16* mid  = (__fp16*)(ws);             // 1605632 B
    __fp16* w1fh = (__fp16*)(ws + 1605632);   // 32768 B
    float*  b1f  = (float*)(ws + 1638400);    // 256 B
    __fp16* cwb  = (__fp16*)(ws + 1638656);   // 131072 B

    k0_setup<<<dim3(64), 256, 0, stream>>>(w1, gamma, beta, mean, var, cw,
                                           w1fh, b1f, cwb);
    k1_conv1<<<dim3(49, 4), 256, 0, stream>>>(x, w1fh, b1f, mid);
    k23_fused<<<dim3(49, 16, 4), 256, 0, stream>>>(x, mid, cwb, cb, out);
}

// Round 9
// 106.603 us; speedup vs baseline: 1.1371x; 1.1371x over previous
//
#include <hip/hip_runtime.h>

// Involution: B=4, C=256, H=W=56, K=7, GC=16 -> G=16, Cr=64, K2=49
// conv1 + conv2 f16 MFMA (16x16x32); apply fp32, b32 lx reads (odd row stride).
// Halo fetched as aligned float4 (all-or-nothing validity), selects at load.
// ws: mid f16 [4][3136 p][64 c] @0 | w1fh f16 [64 o][256 c] BN-folded @1605632 |
//     b1f f32[64] @1638400 | cwb f16 [16 g][64 k][64 c] @1638656

#define EPS 1e-5f

typedef __fp16 half2t __attribute__((ext_vector_type(2)));
typedef __fp16 half8t __attribute__((ext_vector_type(8)));
typedef float floatx4 __attribute__((ext_vector_type(4)));

// ---------------- Kernel 0: weight prep ----------------
__global__ __launch_bounds__(256) void k0_setup(
    const float* __restrict__ w1, const float* __restrict__ gamma,
    const float* __restrict__ beta, const float* __restrict__ mean,
    const float* __restrict__ var, const float* __restrict__ cw,
    __fp16* __restrict__ w1fh, float* __restrict__ b1f,
    __fp16* __restrict__ cwb)
{
    const int tid = blockIdx.x * 256 + threadIdx.x;
    const int n   = gridDim.x * 256;
    for (int idx = tid; idx < 16384; idx += n) {        // w1fh[o][c]
        int o = idx >> 8;
        float s = gamma[o] * rsqrtf(var[o] + EPS);
        w1fh[idx] = (__fp16)(w1[idx] * s);
    }
    for (int idx = tid; idx < 64; idx += n) {           // b1f[o]
        float s = gamma[idx] * rsqrtf(var[idx] + EPS);
        b1f[idx] = beta[idx] - mean[idx] * s;
    }
    for (int idx = tid; idx < 65536; idx += n) {        // cwb[g][k][c]
        int g = idx >> 12, k = (idx >> 6) & 63, c = idx & 63;
        cwb[idx] = (__fp16)((k < 49) ? cw[(g * 49 + k) * 64 + c] : 0.f);
    }
}

// ---------------- Kernel 1: conv1 (1x1, 256->64) + BN + ReLU, MFMA ----------
__global__ __launch_bounds__(256, 2) void k1_conv1(
    const float* __restrict__ x, const __fp16* __restrict__ w1fh,
    const float* __restrict__ b1f, __fp16* __restrict__ mid)
{
    __shared__ __align__(16) __fp16 lxB[64 * 72];    // [px][c-chunk], stride 72
    const int t    = threadIdx.x;
    const int b    = blockIdx.y;
    const int p0   = blockIdx.x * 64;
    const int lane = t & 63, wvid = t >> 6;
    const int mrow = lane & 15, quad = lane >> 4;

    const int orow = wvid * 16 + mrow;
    half8t A[4][2];
#pragma unroll
    for (int ch = 0; ch < 4; ++ch)
#pragma unroll
        for (int h = 0; h < 2; ++h)
            A[ch][h] = *(const half8t*)&w1fh[orow * 256 + ch * 64 + h * 32 + quad * 8];

    floatx4 acc[4] = {};
    const int c2 = t & 31, pxo = t >> 5;             // staging: c-pair, px-octet
    for (int ch = 0; ch < 4; ++ch) {
        const float* r0 = &x[(size_t)(b * 256 + ch * 64 + 2 * c2) * 3136 + p0 + pxo * 8];
        const float* r1 = r0 + 3136;
        float4 a0 = *(const float4*)r0, a1 = *(const float4*)(r0 + 4);
        float4 b0 = *(const float4*)r1, b1 = *(const float4*)(r1 + 4);
        const float* f0 = (const float*)&a0;
        const float* f1 = (const float*)&b0;
#pragma unroll
        for (int j = 0; j < 4; ++j) {
            half2t q = __builtin_amdgcn_cvt_pkrtz(f0[j], f1[j]);
            *(half2t*)&lxB[(pxo * 8 + j) * 72 + 2 * c2] = q;
        }
        const float* g0 = (const float*)&a1;
        const float* g1 = (const float*)&b1;
#pragma unroll
        for (int j = 0; j < 4; ++j) {
            half2t q = __builtin_amdgcn_cvt_pkrtz(g0[j], g1[j]);
            *(half2t*)&lxB[(pxo * 8 + 4 + j) * 72 + 2 * c2] = q;
        }
        __syncthreads();
#pragma unroll
        for (int pt = 0; pt < 4; ++pt) {
            half8t bf0 = *(const half8t*)&lxB[(pt * 16 + mrow) * 72 + quad * 8];
            half8t bf1 = *(const half8t*)&lxB[(pt * 16 + mrow) * 72 + quad * 8 + 32];
            acc[pt] = __builtin_amdgcn_mfma_f32_16x16x32_f16(A[ch][0], bf0, acc[pt], 0, 0, 0);
            acc[pt] = __builtin_amdgcn_mfma_f32_16x16x32_f16(A[ch][1], bf1, acc[pt], 0, 0, 0);
        }
        __syncthreads();
    }
    float bb[4];
#pragma unroll
    for (int i = 0; i < 4; ++i) bb[i] = b1f[wvid * 16 + quad * 4 + i];
#pragma unroll
    for (int pt = 0; pt < 4; ++pt)
#pragma unroll
        for (int i = 0; i < 4; ++i) {
            float v = fmaxf(acc[pt][i] + bb[i], 0.f);
            lxB[(pt * 16 + mrow) * 72 + wvid * 16 + quad * 4 + i] = (__fp16)v;
        }
    __syncthreads();
#pragma unroll
    for (int it = 0; it < 2; ++it) {
        int slot = t + it * 256;
        int px = slot >> 3, o8 = slot & 7;
        *(half8t*)&mid[(size_t)(b * 3136 + p0 + px) * 64 + o8 * 8] =
            *(const half8t*)&lxB[px * 72 + o8 * 8];
    }
}

// ---------------- Kernel 2: fused conv2 (f16 MFMA) + unfold/apply (fp32) ----
__global__ __launch_bounds__(256, 5) void k23_fused(
    const float* __restrict__ x, const __fp16* __restrict__ mid,
    const __fp16* __restrict__ cwb, const float* __restrict__ cb,
    float* __restrict__ out)
{
    // lmid[64px][72] f16 (9216 B) overlaid by lx[16ch][244] f32 (15616 B);
    // lw2[49][68] f32 at 15616 (13328 B). total 28944 B.
    __shared__ __align__(16) unsigned char smem[28944];
    __fp16* lmid = (__fp16*)smem;
    float*  lx   = (float*)smem;                 // ch stride 244, row stride 17
    float*  lw2  = (float*)(smem + 15616);

    const int t  = threadIdx.x;
    const int b  = blockIdx.z;
    const int g  = blockIdx.y;
    const int th = blockIdx.x / 7, tw = blockIdx.x % 7;
    const int h0 = th * 8, w0 = tw * 8;
    const int lane = t & 63, wvid = t >> 6;
    const int mrow = lane & 15, quad = lane >> 4;

    // ---- halo prefetch FIRST: 16ch x 14rows x 4 f4 (cols w0-4..w0+11) ----
    float4 rv4[4];
    int    rslot[4];
#pragma unroll
    for (int i = 0; i < 4; ++i) {
        int s = t + i * 256;
        rslot[i] = s;
        float4 v = make_float4(0.f, 0.f, 0.f, 0.f);
        if (s < 896) {
            int ch = s / 56, r = s % 56;
            int row = r >> 2, q = r & 3;
            int gh = h0 + row - 3;
            int gwb = w0 - 4 + q * 4;
            bool ok = (gh >= 0) & (gh < 56) & (gwb >= 0) & (gwb <= 52);
            int ghc = min(max(gh, 0), 55);
            int gwc = min(max(gwb, 0), 52);
            float4 ld = *(const float4*)&x[(size_t)(b * 256 + g * 16 + ch) * 3136 +
                                           ghc * 56 + gwc];
            if (ok) v = ld;
        }
        rv4[i] = v;
    }

    // A-fragments straight from global (L2-hot, 8 KB per g)
    half8t a0 = *(const half8t*)&cwb[g * 4096 + (wvid * 16 + mrow) * 64 + quad * 8];
    half8t a1 = *(const half8t*)&cwb[g * 4096 + (wvid * 16 + mrow) * 64 + quad * 8 + 32];

    // stage lmid [px][c] (stride 72): contiguous-slot b128 copies
#pragma unroll
    for (int i = 0; i < 2; ++i) {
        int s  = t + i * 256;
        int px = s >> 3, c8 = s & 7;
        int pix = (h0 + (px >> 3)) * 56 + w0 + (px & 7);
        *(half8t*)&lmid[px * 72 + c8 * 8] =
            *(const half8t*)&mid[(size_t)(b * 3136 + pix) * 64 + c8 * 8];
    }
    __syncthreads();

    // MFMA GEMM: D[ko][px] = sum_c W[ko][c] * M[c][px]
    {
        float bias[4];
        int   kor[4];
#pragma unroll
        for (int i = 0; i < 4; ++i) {
            kor[i]  = wvid * 16 + quad * 4 + i;
            bias[i] = (kor[i] < 49) ? cb[g * 49 + kor[i]] : 0.f;
        }
#pragma unroll
        for (int pt = 0; pt < 4; ++pt) {
            half8t b0 = *(const half8t*)&lmid[(pt * 16 + mrow) * 72 + quad * 8];
            half8t b1 = *(const half8t*)&lmid[(pt * 16 + mrow) * 72 + quad * 8 + 32];
            floatx4 acc = {0.f, 0.f, 0.f, 0.f};
            acc = __builtin_amdgcn_mfma_f32_16x16x32_f16(a0, b0, acc, 0, 0, 0);
            acc = __builtin_amdgcn_mfma_f32_16x16x32_f16(a1, b1, acc, 0, 0, 0);
#pragma unroll
            for (int i = 0; i < 4; ++i)
                if (kor[i] < 49)
                    lw2[kor[i] * 68 + pt * 16 + mrow] = acc[i] + bias[i];
        }
    }
    __syncthreads();

    // halo f4 regs -> LDS as 4x b32 (ch stride 244, row stride 17, 16 cols)
#pragma unroll
    for (int i = 0; i < 4; ++i) {
        int s = rslot[i];
        if (s < 896) {
            int ch = s / 56, r = s % 56;
            int row = r >> 2, q = r & 3;
            float* dst = &lx[ch * 244 + row * 17 + q * 4];
            dst[0] = rv4[i].x; dst[1] = rv4[i].y;
            dst[2] = rv4[i].z; dst[3] = rv4[i].w;
        }
    }
    __syncthreads();

    // apply: thread = (cc = t>>4, 4 consecutive out px), fp32, b32 lx reads
    const int cc = t >> 4, pxt = t & 15;
    const int sh = pxt >> 1, sw4 = (pxt & 1) * 4;
    float a0f = 0.f, a1f = 0.f, a2f = 0.f, a3f = 0.f;
#pragma unroll
    for (int kh = 0; kh < 7; ++kh) {
        float xr[10];
        const int base = cc * 244 + (sh + kh) * 17 + sw4 + 1;
#pragma unroll
        for (int j = 0; j < 10; ++j) xr[j] = lx[base + j];
#pragma unroll
        for (int kw = 0; kw < 7; ++kw) {
            const float4 wv = *(const float4*)&lw2[(kh * 7 + kw) * 68 + pxt * 4];
            a0f = fmaf(wv.x, xr[kw + 0], a0f);
            a1f = fmaf(wv.y, xr[kw + 1], a1f);
            a2f = fmaf(wv.z, xr[kw + 2], a2f);
            a3f = fmaf(wv.w, xr[kw + 3], a3f);
        }
    }
    *(float4*)&out[(b * 256 + g * 16 + cc) * 3136 + (h0 + sh) * 56 + w0 + sw4] =
        make_float4(a0f, a1f, a2f, a3f);
}

extern "C" void kernel_launch(void* const* d_in, const int* in_sizes, int n_in,
                              void* d_out, int out_size, void* d_ws, size_t ws_size,
                              hipStream_t stream) {
    const float* x     = (const float*)d_in[0];
    const float* w1    = (const float*)d_in[1];
    const float* gamma = (const float*)d_in[2];
    const float* beta  = (const float*)d_in[3];
    const float* mean  = (const float*)d_in[4];
    const float* var   = (const float*)d_in[5];
    const float* cw    = (const float*)d_in[6];
    const float* cb    = (const float*)d_in[7];
    float* out = (float*)d_out;

    unsigned char* ws = (unsigned char*)d_ws;
    __fp16* mid  = (__fp16*)(ws);             // 1605632 B
    __fp16* w1fh = (__fp16*)(ws + 1605632);   // 32768 B
    float*  b1f  = (float*)(ws + 1638400);    // 256 B
    __fp16* cwb  = (__fp16*)(ws + 1638656);   // 131072 B

    k0_setup<<<dim3(64), 256, 0, stream>>>(w1, gamma, beta, mean, var, cw,
                                           w1fh, b1f, cwb);
    k1_conv1<<<dim3(49, 4), 256, 0, stream>>>(x, w1fh, b1f, mid);
    k23_fused<<<dim3(49, 16, 4), 256, 0, stream>>>(x, mid, cwb, cb, out);
}

// Round 10
// 106.209 us; speedup vs baseline: 1.1413x; 1.0037x over previous
//
#include <hip/hip_runtime.h>

// Involution: B=4, C=256, H=W=56, K=7, GC=16 -> G=16, Cr=64, K2=49
// Two kernels only. conv1 + conv2 f16 MFMA (16x16x32), weights converted
// inline (BN folded into conv1 A-frags); apply fp32, odd-stride LDS banks.
// ws: mid f16 [4][3136 p][64 c] @0 (1605632 B). Nothing else.

#define EPS 1e-5f

typedef __fp16 half2t __attribute__((ext_vector_type(2)));
typedef __fp16 half8t __attribute__((ext_vector_type(8)));
typedef float floatx4 __attribute__((ext_vector_type(4)));

__device__ inline half8t pack8(float4 u0, float4 u1, float s) {
    half8t a;
    half2t q;
    q = __builtin_amdgcn_cvt_pkrtz(u0.x * s, u0.y * s); a[0] = q[0]; a[1] = q[1];
    q = __builtin_amdgcn_cvt_pkrtz(u0.z * s, u0.w * s); a[2] = q[0]; a[3] = q[1];
    q = __builtin_amdgcn_cvt_pkrtz(u1.x * s, u1.y * s); a[4] = q[0]; a[5] = q[1];
    q = __builtin_amdgcn_cvt_pkrtz(u1.z * s, u1.w * s); a[6] = q[0]; a[7] = q[1];
    return a;
}

// ---------------- Kernel 1: conv1 (1x1, 256->64) + BN + ReLU, MFMA ----------
// grid (98,4): block 64o x 32px, K=256 in 4 chunks. A-frags from w1 inline.
__global__ __launch_bounds__(256, 4) void k1_conv1(
    const float* __restrict__ x, const float* __restrict__ w1,
    const float* __restrict__ gamma, const float* __restrict__ beta,
    const float* __restrict__ mean, const float* __restrict__ var,
    __fp16* __restrict__ mid)
{
    __shared__ __align__(16) __fp16 lxB[32 * 72];    // [px][c-chunk], stride 72
    const int t    = threadIdx.x;
    const int b    = blockIdx.y;
    const int p0   = blockIdx.x * 32;
    const int lane = t & 63, wvid = t >> 6;
    const int mrow = lane & 15, quad = lane >> 4;

    // A-fragments: BN scale folded, f32 -> f16 inline (w1 is L2-hot)
    const int orow = wvid * 16 + mrow;
    const float s = gamma[orow] * rsqrtf(var[orow] + EPS);
    half8t A[4][2];
#pragma unroll
    for (int ch = 0; ch < 4; ++ch)
#pragma unroll
        for (int h = 0; h < 2; ++h) {
            const float* src = &w1[orow * 256 + ch * 64 + h * 32 + quad * 8];
            A[ch][h] = pack8(*(const float4*)src, *(const float4*)(src + 4), s);
        }

    floatx4 acc[2] = {};
    const int c2 = t & 31, pxq = t >> 5;             // staging: c-pair, px-quad
    for (int ch = 0; ch < 4; ++ch) {
        const float* r0 = &x[(size_t)(b * 256 + ch * 64 + 2 * c2) * 3136 + p0 + pxq * 4];
        const float* r1 = r0 + 3136;
        float4 a0 = *(const float4*)r0;
        float4 b0 = *(const float4*)r1;
        const float* f0 = (const float*)&a0;
        const float* f1 = (const float*)&b0;
#pragma unroll
        for (int j = 0; j < 4; ++j) {
            half2t q = __builtin_amdgcn_cvt_pkrtz(f0[j], f1[j]);
            *(half2t*)&lxB[(pxq * 4 + j) * 72 + 2 * c2] = q;
        }
        __syncthreads();
#pragma unroll
        for (int pt = 0; pt < 2; ++pt) {
            half8t bf0 = *(const half8t*)&lxB[(pt * 16 + mrow) * 72 + quad * 8];
            half8t bf1 = *(const half8t*)&lxB[(pt * 16 + mrow) * 72 + quad * 8 + 32];
            acc[pt] = __builtin_amdgcn_mfma_f32_16x16x32_f16(A[ch][0], bf0, acc[pt], 0, 0, 0);
            acc[pt] = __builtin_amdgcn_mfma_f32_16x16x32_f16(A[ch][1], bf1, acc[pt], 0, 0, 0);
        }
        __syncthreads();
    }
    // epilogue: per-lane bias + relu -> f16, transpose via lxB, b128 out
    float bb[4];
#pragma unroll
    for (int i = 0; i < 4; ++i) {
        int o = wvid * 16 + quad * 4 + i;
        float so = gamma[o] * rsqrtf(var[o] + EPS);
        bb[i] = beta[o] - mean[o] * so;
    }
#pragma unroll
    for (int pt = 0; pt < 2; ++pt)
#pragma unroll
        for (int i = 0; i < 4; ++i) {
            float v = fmaxf(acc[pt][i] + bb[i], 0.f);
            lxB[(pt * 16 + mrow) * 72 + wvid * 16 + quad * 4 + i] = (__fp16)v;
        }
    __syncthreads();
    {
        int px = t >> 3, o8 = t & 7;                 // 256 slots = 32px x 8
        *(half8t*)&mid[(size_t)(b * 3136 + p0 + px) * 64 + o8 * 8] =
            *(const half8t*)&lxB[px * 72 + o8 * 8];
    }
}

// ---------------- Kernel 2: fused conv2 (f16 MFMA) + unfold/apply (fp32) ----
__global__ __launch_bounds__(256, 5) void k23_fused(
    const float* __restrict__ x, const __fp16* __restrict__ mid,
    const float* __restrict__ cw, const float* __restrict__ cb,
    float* __restrict__ out)
{
    // lmid[64px][72] f16 (9216 B) overlaid by lx[16ch][244] f32 (15616 B);
    // lw2[49][68] f32 at 15616 (13328 B). total 28944 B.
    __shared__ __align__(16) unsigned char smem[28944];
    __fp16* lmid = (__fp16*)smem;
    float*  lx   = (float*)smem;                 // ch stride 244, row stride 17
    float*  lw2  = (float*)(smem + 15616);

    const int t  = threadIdx.x;
    const int b  = blockIdx.z;
    const int g  = blockIdx.y;
    const int th = blockIdx.x / 7, tw = blockIdx.x % 7;
    const int h0 = th * 8, w0 = tw * 8;
    const int lane = t & 63, wvid = t >> 6;
    const int mrow = lane & 15, quad = lane >> 4;

    // ---- halo prefetch FIRST: 16ch x 14rows x 4 f4 (cols w0-4..w0+11) ----
    float4 rv4[4];
    int    rslot[4];
#pragma unroll
    for (int i = 0; i < 4; ++i) {
        int s = t + i * 256;
        rslot[i] = s;
        float4 v = make_float4(0.f, 0.f, 0.f, 0.f);
        if (s < 896) {
            int ch = s / 56, r = s % 56;
            int row = r >> 2, q = r & 3;
            int gh = h0 + row - 3;
            int gwb = w0 - 4 + q * 4;
            bool ok = (gh >= 0) & (gh < 56) & (gwb >= 0) & (gwb <= 52);
            int ghc = min(max(gh, 0), 55);
            int gwc = min(max(gwb, 0), 52);
            float4 ld = *(const float4*)&x[(size_t)(b * 256 + g * 16 + ch) * 3136 +
                                           ghc * 56 + gwc];
            if (ok) v = ld;
        }
        rv4[i] = v;
    }

    // A-fragments: cw f32 -> f16 inline (L2-hot); rows >=49 are zero
    const int krow = wvid * 16 + mrow;
    half8t a0 = {}, a1 = {};
    if (krow < 49) {
        const float* src = &cw[(size_t)(g * 49 + krow) * 64 + quad * 8];
        a0 = pack8(*(const float4*)src,        *(const float4*)(src + 4),  1.f);
        a1 = pack8(*(const float4*)(src + 32), *(const float4*)(src + 36), 1.f);
    }

    // stage lmid [px][c] (stride 72): contiguous-slot b128 copies
#pragma unroll
    for (int i = 0; i < 2; ++i) {
        int s  = t + i * 256;
        int px = s >> 3, c8 = s & 7;
        int pix = (h0 + (px >> 3)) * 56 + w0 + (px & 7);
        *(half8t*)&lmid[px * 72 + c8 * 8] =
            *(const half8t*)&mid[(size_t)(b * 3136 + pix) * 64 + c8 * 8];
    }
    __syncthreads();

    // MFMA GEMM: D[ko][px] = sum_c W[ko][c] * M[c][px]
    {
        float bias[4];
        int   kor[4];
#pragma unroll
        for (int i = 0; i < 4; ++i) {
            kor[i]  = wvid * 16 + quad * 4 + i;
            bias[i] = (kor[i] < 49) ? cb[g * 49 + kor[i]] : 0.f;
        }
#pragma unroll
        for (int pt = 0; pt < 4; ++pt) {
            half8t b0 = *(const half8t*)&lmid[(pt * 16 + mrow) * 72 + quad * 8];
            half8t b1 = *(const half8t*)&lmid[(pt * 16 + mrow) * 72 + quad * 8 + 32];
            floatx4 acc = {0.f, 0.f, 0.f, 0.f};
            acc = __builtin_amdgcn_mfma_f32_16x16x32_f16(a0, b0, acc, 0, 0, 0);
            acc = __builtin_amdgcn_mfma_f32_16x16x32_f16(a1, b1, acc, 0, 0, 0);
#pragma unroll
            for (int i = 0; i < 4; ++i)
                if (kor[i] < 49)
                    lw2[kor[i] * 68 + pt * 16 + mrow] = acc[i] + bias[i];
        }
    }
    __syncthreads();

    // halo f4 regs -> LDS as 4x b32 (ch stride 244, row stride 17, 16 cols)
#pragma unroll
    for (int i = 0; i < 4; ++i) {
        int s = rslot[i];
        if (s < 896) {
            int ch = s / 56, r = s % 56;
            int row = r >> 2, q = r & 3;
            float* dst = &lx[ch * 244 + row * 17 + q * 4];
            dst[0] = rv4[i].x; dst[1] = rv4[i].y;
            dst[2] = rv4[i].z; dst[3] = rv4[i].w;
        }
    }
    __syncthreads();

    // apply: thread = (cc = t>>4, 4 consecutive out px), fp32, b32 lx reads
    const int cc = t >> 4, pxt = t & 15;
    const int sh = pxt >> 1, sw4 = (pxt & 1) * 4;
    float a0f = 0.f, a1f = 0.f, a2f = 0.f, a3f = 0.f;
#pragma unroll
    for (int kh = 0; kh < 7; ++kh) {
        float xr[10];
        const int base = cc * 244 + (sh + kh) * 17 + sw4 + 1;
#pragma unroll
        for (int j = 0; j < 10; ++j) xr[j] = lx[base + j];
#pragma unroll
        for (int kw = 0; kw < 7; ++kw) {
            const float4 wv = *(const float4*)&lw2[(kh * 7 + kw) * 68 + pxt * 4];
            a0f = fmaf(wv.x, xr[kw + 0], a0f);
            a1f = fmaf(wv.y, xr[kw + 1], a1f);
            a2f = fmaf(wv.z, xr[kw + 2], a2f);
            a3f = fmaf(wv.w, xr[kw + 3], a3f);
        }
    }
    *(float4*)&out[(b * 256 + g * 16 + cc) * 3136 + (h0 + sh) * 56 + w0 + sw4] =
        make_float4(a0f, a1f, a2f, a3f);
}

extern "C" void kernel_launch(void* const* d_in, const int* in_sizes, int n_in,
                              void* d_out, int out_size, void* d_ws, size_t ws_size,
                              hipStream_t stream) {
    const float* x     = (const float*)d_in[0];
    const float* w1    = (const float*)d_in[1];
    const float* gamma = (const float*)d_in[2];
    const float* beta  = (const float*)d_in[3];
    const float* mean  = (const float*)d_in[4];
    const float* var   = (const float*)d_in[5];
    const float* cw    = (const float*)d_in[6];
    const float* cb    = (const float*)d_in[7];
    float* out = (float*)d_out;

    __fp16* mid = (__fp16*)d_ws;             // 1605632 B

    k1_conv1<<<dim3(98, 4), 256, 0, stream>>>(x, w1, gamma, beta, mean, var, mid);
    k23_fused<<<dim3(49, 16, 4), 256, 0, stream>>>(x, mid, cw, cb, out);
}